// Round 1
// baseline (12178.976 us; speedup 1.0000x reference)
//
#include <hip/hip_runtime.h>

// ---------------- problem constants ----------------
#define NLAYER 64
#define HID    50
#define DIN    60
#define DOUT   50
#define BATCH  32
#define NT     2048
#define NG     200          // 4*HID
#define DEPTH  16           // ring depth (power of two)
#define BS     8            // batch slice per block (BATCH/4)

// ---------------- workspace layout ----------------
#define FLAGS_WORDS (NLAYER*4*NT)            // one-shot produce flags [l][q][t]
#define CONS_WORDS  256                      // consumer progress counters [l*4+q]
#define RING_ROW    52                       // padded H row (13 float4)
#define RING_SLOT   (BATCH*RING_ROW)         // 1664 floats per slot
#define RING_WORDS  ((size_t)63*DEPTH*RING_SLOT)
#define RING_OFF    ((size_t)(FLAGS_WORDS + CONS_WORDS)*4)
#define Y63_OFF     (RING_OFF + RING_WORDS*4)

// ---------------- output layout ----------------
#define HS_OFF ((size_t)BATCH*DOUT*NT)                 // 3,276,800
#define CS_OFF (HS_OFF + (size_t)NLAYER*BATCH*HID)     // +102,400

typedef float f4 __attribute__((ext_vector_type(4)));

// ---- LLC-coherent (cross-XCD) access helpers: bypass L1/L2 via sc0 sc1 ----
__device__ __forceinline__ unsigned llc_load_u32(const unsigned* p) {
  unsigned r;
  asm volatile("global_load_dword %0, %1, off sc0 sc1\n\ts_waitcnt vmcnt(0)"
               : "=v"(r) : "v"(p) : "memory");
  return r;
}
__device__ __forceinline__ void llc_store_u32(unsigned* p, unsigned v) {
  asm volatile("global_store_dword %0, %1, off sc0 sc1" :: "v"(p), "v"(v) : "memory");
}
__device__ __forceinline__ f4 llc_load_f4(const float* p) {
  f4 r;
  asm volatile("global_load_dwordx4 %0, %1, off sc0 sc1\n\ts_waitcnt vmcnt(0)"
               : "=v"(r) : "v"(p) : "memory");
  return r;
}
__device__ __forceinline__ void llc_store_f32(float* p, float v) {
  asm volatile("global_store_dword %0, %1, off sc0 sc1" :: "v"(p), "v"(v) : "memory");
}

__device__ __forceinline__ float sigf(float v)  { return 1.f / (1.f + __expf(-v)); }
__device__ __forceinline__ float tanhx(float v) { return 2.f / (1.f + __expf(-2.f*v)) - 1.f; }

// =====================================================================
// Persistent pipelined LSTM: 256 blocks = 64 layers x 4 batch-quarters.
// Block (l,q): weights for its layer in registers (2 gate rows / thread),
// streams h/x from LDS (uniform b128 broadcasts), exchanges gates via LDS,
// hands y to layer l+1 through an LLC ring with one-shot flags.
// =====================================================================
__global__ __launch_bounds__(256, 1) void lstm_pipe(
    const float* __restrict__ x,   const float* __restrict__ hn,
    const float* __restrict__ cn,  const float* __restrict__ Wih0,
    const float* __restrict__ Wih, const float* __restrict__ Whh,
    const float* __restrict__ bih, const float* __restrict__ bhh,
    unsigned* flags, int* cons, float* ring, float* y63, float* out)
{
  __shared__ float h_lds[BS*52];     // h(t-1), rows padded to 52 (zeros at 50,51)
  __shared__ float x_lds[BS*64];     // layer input, rows padded to 64 (zeros >= KX)
  __shared__ float g_lds[BS*NG];     // gate exchange buffer

  const int tid = threadIdx.x;
  const int bid = blockIdx.x;
  // layer->XCD grouping: XCD x hosts layers [8x, 8x+8) (assuming bid%8 round-robin;
  // if wrong, only locality suffers, never correctness)
  const int xcd = bid & 7, jj = bid >> 3;
  const int l = xcd*8 + (jj >> 2);
  const int q = jj & 3;

  // ---------- one-time: weights into registers ----------
  float wih0[60], wih1[60], whh0[52], whh1[52];
  float bias0 = 0.f, bias1 = 0.f, c0 = 0.f, c1 = 0.f;
  const int p  = tid % 100, bh = tid / 100;   // meaningful for tid<200
  const int r0 = 2*p, r1 = r0 + 1, b0 = bh*4;
  if (tid < 200) {
    const float *wr0, *wr1; int KX;
    if (l == 0) { wr0 = Wih0 + r0*DIN; wr1 = Wih0 + r1*DIN; KX = DIN; }
    else {
      wr0 = Wih + ((size_t)(l-1)*NG + r0)*HID;
      wr1 = Wih + ((size_t)(l-1)*NG + r1)*HID;
      KX = HID;
    }
#pragma unroll
    for (int k = 0; k < 60; ++k) {
      wih0[k] = (k < KX) ? wr0[k] : 0.f;
      wih1[k] = (k < KX) ? wr1[k] : 0.f;
    }
    const float* hr0 = Whh + ((size_t)l*NG + r0)*HID;
    const float* hr1 = Whh + ((size_t)l*NG + r1)*HID;
#pragma unroll
    for (int k = 0; k < 52; ++k) {
      whh0[k] = (k < HID) ? hr0[k] : 0.f;
      whh1[k] = (k < HID) ? hr1[k] : 0.f;
    }
    bias0 = bih[l*NG + r0] + bhh[l*NG + r0];
    bias1 = bih[l*NG + r1] + bhh[l*NG + r1];
    // cell-state ownership: thread owns cells u=tid and u=tid+200 (u = b*HID + j)
    const int u1 = tid, u2 = tid + 200;
    c0 = cn[((size_t)l*BATCH + q*BS + u1/HID)*HID + u1%HID];
    c1 = cn[((size_t)l*BATCH + q*BS + u2/HID)*HID + u2%HID];
  }
  for (int idx = tid; idx < BS*52; idx += 256) {
    const int b = idx/52, j = idx%52;
    h_lds[idx] = (j < HID) ? hn[((size_t)l*BATCH + q*BS + b)*HID + j] : 0.f;
  }
  for (int idx = tid; idx < BS*64; idx += 256) x_lds[idx] = 0.f;
  __syncthreads();

  const unsigned* flag_in  = flags + ((l-1)*4 + q)*NT;   // only deref'd if l>0
  unsigned*       flag_out = flags + (l*4 + q)*NT;
  int* cons_self = cons + (l*4 + q);
  int* cons_next = cons + ((l+1)*4 + q);                 // only deref'd if l<63

  for (int t = 0; t < NT; ++t) {
    const int slot = t & (DEPTH-1);
    // ---- phase A: waits (producer flag + ring backpressure) ----
    if (tid == 0) {
      if (l > 0) {
        while (llc_load_u32(flag_in + t) == 0u) __builtin_amdgcn_s_sleep(1);
      }
      if (l < 63 && t >= DEPTH) {
        const int need = t - DEPTH + 1;
        while (__hip_atomic_load(cons_next, __ATOMIC_RELAXED, __HIP_MEMORY_SCOPE_AGENT) < need)
          __builtin_amdgcn_s_sleep(1);
      }
    }
    __syncthreads();   // B0

    // ---- stage this step's input into x_lds ----
    if (l == 0) {
      for (int idx = tid; idx < BS*DIN; idx += 256) {
        const int b = idx/DIN, d = idx%DIN;
        x_lds[b*64 + d] = x[((size_t)(q*BS + b)*DIN + d)*NT + t];
      }
    } else {
      if (tid < 104) {
        const int b = tid/13, k4 = tid%13;
        f4 v = llc_load_f4(ring + (size_t)((l-1)*DEPTH + slot)*RING_SLOT
                                + (q*BS + b)*RING_ROW + k4*4);
        *(f4*)&x_lds[b*64 + k4*4] = v;
      }
    }
    __syncthreads();   // B1
    if (tid == 0 && l > 0)
      __hip_atomic_store(cons_self, t+1, __ATOMIC_RELAXED, __HIP_MEMORY_SCOPE_AGENT);

    // ---- GEMM: gates = bias + Wih*x + Whh*h (2 rows x 4 batch per thread) ----
    if (tid < 200) {
      float a0[4], a1[4];
#pragma unroll
      for (int b = 0; b < 4; ++b) { a0[b] = bias0; a1[b] = bias1; }
#pragma unroll
      for (int k4 = 0; k4 < 15; ++k4) {
#pragma unroll
        for (int b = 0; b < 4; ++b) {
          f4 xv = *(const f4*)&x_lds[(b0+b)*64 + k4*4];
#pragma unroll
          for (int j = 0; j < 4; ++j) {
            a0[b] = fmaf(xv[j], wih0[4*k4+j], a0[b]);
            a1[b] = fmaf(xv[j], wih1[4*k4+j], a1[b]);
          }
        }
      }
#pragma unroll
      for (int k4 = 0; k4 < 13; ++k4) {
#pragma unroll
        for (int b = 0; b < 4; ++b) {
          f4 hv = *(const f4*)&h_lds[(b0+b)*52 + k4*4];
#pragma unroll
          for (int j = 0; j < 4; ++j) {
            a0[b] = fmaf(hv[j], whh0[4*k4+j], a0[b]);
            a1[b] = fmaf(hv[j], whh1[4*k4+j], a1[b]);
          }
        }
      }
#pragma unroll
      for (int b = 0; b < 4; ++b) {
        g_lds[(b0+b)*NG + r0] = a0[b];
        g_lds[(b0+b)*NG + r1] = a1[b];
      }
    }
    __syncthreads();   // B2

    // ---- elementwise LSTM update (2 cells per thread, c in registers) ----
    if (tid < 200) {
#pragma unroll
      for (int half = 0; half < 2; ++half) {
        const int u = tid + half*200;
        const int b = u / HID, j = u % HID;
        const float cprev = half ? c1 : c0;
        const float gi = g_lds[b*NG + j];
        const float gf = g_lds[b*NG +  50 + j];
        const float gg = g_lds[b*NG + 100 + j];
        const float go = g_lds[b*NG + 150 + j];
        const float cc = sigf(gf)*cprev + sigf(gi)*tanhx(gg);
        const float hh = sigf(go)*tanhx(cc);
        if (half) c1 = cc; else c0 = cc;
        h_lds[b*52 + j] = hh;
        const int bg = q*BS + b;
        if (l < 63)
          llc_store_f32(ring + (size_t)(l*DEPTH + slot)*RING_SLOT + bg*RING_ROW + j, hh);
        else
          y63[((size_t)t*BATCH + bg)*HID + j] = hh;
        if (t == NT-1) {
          out[HS_OFF + (size_t)l*BATCH*HID + bg*HID + j] = hh;
          out[CS_OFF + (size_t)l*BATCH*HID + bg*HID + j] = cc;
        }
      }
    }
    __syncthreads();   // B3 (drains all waves' stores before flag publish)
    if (tid == 0 && l < 63) llc_store_u32(flag_out + t, 1u);
  }
}

// =====================================================================
// FC head: out[b][d][t] = sigmoid(y63[t][b][:] . fc_w[d][:] + fc_b[d])
// block = (b, 64-t chunk); writes coalesced along t.
// =====================================================================
__global__ __launch_bounds__(320, 1) void fc_kernel(
    const float* __restrict__ y63, const float* __restrict__ fcw,
    const float* __restrict__ fcb, float* __restrict__ out)
{
  __shared__ float y_lds[64*52];
  __shared__ float w_lds[50*52];
  __shared__ float b_lds[50];
  const int tid = threadIdx.x;
  const int b  = blockIdx.x >> 5;
  const int t0 = (blockIdx.x & 31) * 64;
  for (int idx = tid; idx < 64*52; idx += 320) {
    const int r = idx / 52, j = idx % 52;
    y_lds[idx] = (j < HID) ? y63[((size_t)(t0 + r)*BATCH + b)*HID + j] : 0.f;
  }
  for (int idx = tid; idx < 50*52; idx += 320) {
    const int r = idx / 52, j = idx % 52;
    w_lds[idx] = (j < HID) ? fcw[r*HID + j] : 0.f;
  }
  if (tid < 50) b_lds[tid] = fcb[tid];
  __syncthreads();
  const int toff = tid & 63, dg = tid >> 6;   // dg in [0,5)
  for (int d = dg; d < DOUT; d += 5) {
    float acc = b_lds[d];
#pragma unroll
    for (int j4 = 0; j4 < 13; ++j4) {
      f4 yv = *(const f4*)&y_lds[toff*52 + j4*4];
      f4 wv = *(const f4*)&w_lds[d*52 + j4*4];
#pragma unroll
      for (int j = 0; j < 4; ++j) acc = fmaf(yv[j], wv[j], acc);
    }
    out[((size_t)b*DOUT + d)*NT + t0 + toff] = 1.f / (1.f + __expf(-acc));
  }
}

extern "C" void kernel_launch(void* const* d_in, const int* in_sizes, int n_in,
                              void* d_out, int out_size, void* d_ws, size_t ws_size,
                              hipStream_t stream)
{
  const float* x    = (const float*)d_in[0];
  const float* hn   = (const float*)d_in[1];
  const float* cn   = (const float*)d_in[2];
  const float* Wih0 = (const float*)d_in[3];
  const float* Wih  = (const float*)d_in[4];
  const float* Whh  = (const float*)d_in[5];
  const float* bih  = (const float*)d_in[6];
  const float* bhh  = (const float*)d_in[7];
  const float* fcw  = (const float*)d_in[8];
  const float* fcb  = (const float*)d_in[9];
  float* out = (float*)d_out;

  unsigned* flags = (unsigned*)d_ws;
  int*      cons  = (int*)((char*)d_ws + (size_t)FLAGS_WORDS*4);
  float*    ring  = (float*)((char*)d_ws + RING_OFF);
  float*    y63   = (float*)((char*)d_ws + Y63_OFF);
  (void)cons; (void)in_sizes; (void)n_in; (void)out_size; (void)ws_size;

  // flags + cons must be zero every call (ws is re-poisoned 0xAA)
  hipMemsetAsync(d_ws, 0, RING_OFF, stream);

  hipLaunchKernelGGL(lstm_pipe, dim3(256), dim3(256), 0, stream,
                     x, hn, cn, Wih0, Wih, Whh, bih, bhh,
                     flags, (int*)((char*)d_ws + (size_t)FLAGS_WORDS*4), ring, y63, out);
  hipLaunchKernelGGL(fc_kernel, dim3(1024), dim3(320), 0, stream, y63, fcw, fcb, out);
}